// Round 5
// baseline (154.862 us; speedup 1.0000x reference)
//
#include <hip/hip_runtime.h>
#include <hip/hip_bf16.h>

#define BATCH   32768
#define DIM     2048
#define NHEADS  28
#define NCOLS   280
#define LOSS_SCALE (1.0f / (float)(BATCH * NHEADS))

typedef __attribute__((ext_vector_type(8))) short short8;
typedef __attribute__((ext_vector_type(4))) float f32x4;

__device__ __forceinline__ short f2bf(float f) {
    union { __hip_bfloat16 h; short s; } u; u.h = __float2bfloat16(f); return u.s;
}

// ---------------------------------------------------------------------------
// W pre-swizzle: W [280][2048] f32 -> Wswz bf16 in MFMA B-fragment order.
//   short index = (nt*64 + ktg)*512 + lane*8 + j
//   n = nt*16 + (lane&15), d = ktg*32 + (lane>>4)*8 + j   (ktg = K-granule of 32
//   = the GEMM's BK=32 tile index)
// ---------------------------------------------------------------------------
__global__ void mvh_swz(const float* __restrict__ W, short* __restrict__ Wswz) {
    int t = blockIdx.x * 256 + threadIdx.x;      // 73728 threads
    int lane = t & 63;
    int ks = (t >> 6) & 63;
    int nt = t >> 12;                            // 0..17
    int n = nt * 16 + (lane & 15);
    int d = ks * 32 + (lane >> 4) * 8;
    short8 v;
    #pragma unroll
    for (int j = 0; j < 8; j++) v[j] = 0;
    if (n < NCOLS) {
        const float* src = W + (size_t)n * DIM + d;
        #pragma unroll
        for (int j = 0; j < 8; j++) v[j] = f2bf(src[j]);
    }
    *(short8*)(Wswz + (size_t)t * 8) = v;
}

// ---------------------------------------------------------------------------
// GEMM: logits[b][n] = sum_d hidden[b][d]*W[n][d] + bias[n]
// grid 512 x 256 threads (4 waves). BM=64, BK=32, 64 K-tiles, 3 blocks/CU.
// Wave = 32 rows (wsub=wave>>1) x 144 cols (nhalf=wave&1); acc 2x9 f32x4.
// A: fp32 global -> regs (T14 early-issue) -> bf16 cvt -> frag-major LDS.
// B: global_load_lds DMA from frag-ordered L2-resident Wswz.
// Both double-buffered; ONE __syncthreads per tile; counted vmcnt(5) lets
// the 5 B-DMAs stay in flight while A regs are consumed.
// LDS traffic: ~540 B per MFMA (B-frag 1KB/2, A-frag 1KB/9, +writes).
// ---------------------------------------------------------------------------
#define A_TILE 4096
#define B_TILE 18432

#define WAITVM(N) asm volatile("s_waitcnt vmcnt(" #N ")" ::: "memory")
#define SB0() __builtin_amdgcn_sched_barrier(0)

__global__ __launch_bounds__(256, 3)
void mvh_gemm(const float* __restrict__ hidden, const short* __restrict__ Wswz,
              const float* __restrict__ bias, float* __restrict__ logits) {
    __shared__ __align__(16) char lds[2 * A_TILE + 2 * B_TILE];   // 45056 B
    char* A0 = lds;
    char* A1 = lds + A_TILE;
    char* B0 = lds + 2 * A_TILE;
    char* B1 = lds + 2 * A_TILE + B_TILE;

    const int tid  = threadIdx.x;
    const int lane = tid & 63;
    const int wave = tid >> 6;          // 0..3
    const int nhalf = wave & 1;         // 144-col half
    const int wsub  = wave >> 1;        // 32-row slice
    const int l15 = lane & 15, lhi = lane >> 4;
    const int rowbase = blockIdx.x * 64;

    // A staging map: thread t stages frag fi=t>>6, frag-lane t&63:
    //   row = fi*16 + (t&15), k0 = ((t>>4)&3)*8  -> 8 consecutive floats.
    // 4 lanes per row cover 128B contiguous -> full-line HBM requests.
    const int arow = (tid >> 6) * 16 + (tid & 15);
    const int ak0  = ((tid >> 4) & 3) * 8;
    const float* gAbase = hidden + (size_t)(rowbase + arow) * DIM + ak0;

    f32x4 acc0[9], acc1[9];
    #pragma unroll
    for (int n = 0; n < 9; n++) { acc0[n] = (f32x4)0.0f; acc1[n] = (f32x4)0.0f; }

    f32x4 ga0, ga1;   // in-flight A (consumed within the same phase)

#define LOADA(kt) do { \
    const float* p_ = gAbase + (kt) * 32; \
    ga0 = *(const f32x4*)(p_); \
    ga1 = *(const f32x4*)(p_ + 4); \
    SB0(); \
} while (0)

#define STAGE_B(dst, kt) do { \
    _Pragma("unroll") \
    for (int i_ = 0; i_ < 5; i_++) { \
        if (i_ < 4 || tid < 128) { \
            int g_ = i_ * 256 + tid; \
            const short* gp_ = Wswz + (size_t)((g_ >> 6) * 64 + (kt)) * 512 + (g_ & 63) * 8; \
            char* lp_ = (dst) + g_ * 16; \
            __builtin_amdgcn_global_load_lds((const __attribute__((address_space(1))) void*)gp_, \
                (__attribute__((address_space(3))) void*)lp_, 16, 0, 0); \
        } \
    } \
    SB0(); \
} while (0)

#define WRITEA(dst) do { \
    short8 s_; \
    _Pragma("unroll") \
    for (int j_ = 0; j_ < 4; j_++) { s_[j_] = f2bf(ga0[j_]); s_[4 + j_] = f2bf(ga1[j_]); } \
    *(short8*)((dst) + tid * 16) = s_; \
} while (0)

#define COMPUTE(Ab, Bb) do { \
    short8 af0_ = *(const short8*)((Ab) + (wsub * 2 + 0) * 1024 + lane * 16); \
    short8 af1_ = *(const short8*)((Ab) + (wsub * 2 + 1) * 1024 + lane * 16); \
    _Pragma("unroll") \
    for (int n_ = 0; n_ < 9; n_++) { \
        short8 bf_ = *(const short8*)((Bb) + (nhalf * 9 + n_) * 1024 + lane * 16); \
        acc0[n_] = __builtin_amdgcn_mfma_f32_16x16x32_bf16(af0_, bf_, acc0[n_], 0, 0, 0); \
        acc1[n_] = __builtin_amdgcn_mfma_f32_16x16x32_bf16(af1_, bf_, acc1[n_], 0, 0, 0); \
    } \
} while (0)

    // ---- prologue: tile 0 -> buffers 0 ----
    LOADA(0);
    STAGE_B(B0, 0);
    WAITVM(5); SB0();
    WRITEA(A0);
    __syncthreads();

    // ---- main loop: even/odd bodies, one barrier per tile ----
    #pragma unroll 1
    for (int t = 0; t < 62; t += 2) {
        // compute tile t (buf0), stage t+1 -> buf1
        LOADA(t + 1);
        STAGE_B(B1, t + 1);
        COMPUTE(A0, B0);
        WAITVM(5); SB0();
        WRITEA(A1);
        __syncthreads();
        // compute tile t+1 (buf1), stage t+2 -> buf0
        LOADA(t + 2);
        STAGE_B(B0, t + 2);
        COMPUTE(A1, B1);
        WAITVM(5); SB0();
        WRITEA(A0);
        __syncthreads();
    }
    // tile 62 (buf0), stage 63 -> buf1
    LOADA(63);
    STAGE_B(B1, 63);
    COMPUTE(A0, B0);
    WAITVM(5); SB0();
    WRITEA(A1);
    __syncthreads();
    // tile 63 (buf1)
    COMPUTE(A1, B1);

#undef LOADA
#undef STAGE_B
#undef WRITEA
#undef COMPUTE

    // epilogue: bias + store. D frag: row = lhi*4 + r, col = l15.
    #pragma unroll
    for (int n = 0; n < 9; n++) {
        int c = nhalf * 144 + n * 16 + l15;
        if (c < NCOLS) {
            float bv = bias[c];
            int row0 = rowbase + wsub * 32 + lhi * 4;
            #pragma unroll
            for (int r = 0; r < 4; r++) {
                logits[(size_t)(row0 + r) * NCOLS + c]      = acc0[n][r] + bv;
                logits[(size_t)(row0 + 16 + r) * NCOLS + c] = acc1[n][r] + bv;
            }
        }
    }
}

// ---------------------------------------------------------------------------
// Loss: one thread per (row, head). nll = logsumexp(10) - x[label].
// ---------------------------------------------------------------------------
__global__ __launch_bounds__(256)
void mvh_loss(const float* __restrict__ logits, const int* __restrict__ labels,
              float* __restrict__ loss_out) {
    int gid = blockIdx.x * 256 + threadIdx.x;    // 917504 = 3584*256 exactly
    const float* p = logits + (size_t)gid * 10;
    float x[10];
    #pragma unroll
    for (int j = 0; j < 10; j++) x[j] = p[j];
    float m = x[0];
    #pragma unroll
    for (int j = 1; j < 10; j++) m = fmaxf(m, x[j]);
    float s = 0.0f;
    #pragma unroll
    for (int j = 0; j < 10; j++) s += __expf(x[j] - m);
    int lab = labels[gid];
    float xl = x[0];
    #pragma unroll
    for (int j = 1; j < 10; j++) xl = (lab == j) ? x[j] : xl;
    float nll = m + __logf(s) - xl;

    #pragma unroll
    for (int off = 32; off > 0; off >>= 1)
        nll += __shfl_down(nll, off, 64);

    __shared__ float part[4];
    int lane = threadIdx.x & 63, wv = threadIdx.x >> 6;
    if (lane == 0) part[wv] = nll;
    __syncthreads();
    if (threadIdx.x == 0)
        atomicAdd(loss_out, (part[0] + part[1] + part[2] + part[3]) * LOSS_SCALE);
}

extern "C" void kernel_launch(void* const* d_in, const int* in_sizes, int n_in,
                              void* d_out, int out_size, void* d_ws, size_t ws_size,
                              hipStream_t stream) {
    const float* hidden = (const float*)d_in[0];
    const int* labels   = (const int*)d_in[1];
    const float* W      = (const float*)d_in[2];
    const float* bias   = (const float*)d_in[3];
    float* out = (float*)d_out;
    short* Wswz = (short*)d_ws;   // 589824 bf16 = 1.18 MB

    hipMemsetAsync(d_out, 0, sizeof(float), stream);           // zero loss accumulator
    mvh_swz<<<288, 256, 0, stream>>>(W, Wswz);
    mvh_gemm<<<512, 256, 0, stream>>>(hidden, Wswz, bias, out + 1);
    mvh_loss<<<3584, 256, 0, stream>>>(out + 1, labels, out);
}

// Round 6
// 146.442 us; speedup vs baseline: 1.0575x; 1.0575x over previous
//
#include <hip/hip_runtime.h>
#include <hip/hip_bf16.h>

#define BATCH   32768
#define DIM     2048
#define NHEADS  28
#define NCOLS   280
#define LOSS_SCALE (1.0f / (float)(BATCH * NHEADS))

typedef __attribute__((ext_vector_type(8))) short short8;
typedef __attribute__((ext_vector_type(4))) float f32x4;

__device__ __forceinline__ short f2bf(float f) {
    union { __hip_bfloat16 h; short s; } u; u.h = __float2bfloat16(f); return u.s;
}

// ---------------------------------------------------------------------------
// W pre-swizzle: W [280][2048] f32 -> Wswz bf16 in MFMA B-fragment order.
//   short index = (nt*64 + kt)*512 + lane*8 + j
//   n = nt*16 + (lane&15), d = kt*32 + (lane>>4)*8 + j   (kt = BK=32 tile idx)
// ---------------------------------------------------------------------------
__global__ void mvh_swz(const float* __restrict__ W, short* __restrict__ Wswz) {
    int t = blockIdx.x * 256 + threadIdx.x;      // 73728 threads
    int lane = t & 63;
    int ks = (t >> 6) & 63;
    int nt = t >> 12;                            // 0..17
    int n = nt * 16 + (lane & 15);
    int d = ks * 32 + (lane >> 4) * 8;
    short8 v;
    #pragma unroll
    for (int j = 0; j < 8; j++) v[j] = 0;
    if (n < NCOLS) {
        const float* src = W + (size_t)n * DIM + d;
        #pragma unroll
        for (int j = 0; j < 8; j++) v[j] = f2bf(src[j]);
    }
    *(short8*)(Wswz + (size_t)t * 8) = v;
}

// ---------------------------------------------------------------------------
// GEMM: logits[b][n] = sum_d hidden[b][d]*W[n][d] + bias[n]
// grid 512 x 512 threads (8 waves) -> 2 blocks/CU = 16 waves/CU.
// BM=64, BK=32, 64 K-tiles. Waves: kph=w>>2 (tile parity; kph0 owns buf0),
// wsub=(w>>1)&1 (32 rows), nhalf=w&1 (144 cols). M_rep=2: acc 2x9 f32x4.
// A: 1 f32x4/thread global load issued 2 tiles ahead (alive across raw
//    barriers, tail-counted vmcnt), cvt->bf16 frag-major LDS (dbuf).
// B: global_load_lds DMA from L2-resident frag-ordered Wswz (dbuf).
// One raw barrier per tile; counted vmcnt(1) keeps next A in flight.
// Epilogue: 2-phase cross-kph LDS reduction + bias + store.
// ---------------------------------------------------------------------------
#define A_TILE 4096
#define B_TILE 18432

#define WAITVM(N)   asm volatile("s_waitcnt vmcnt(" #N ")" ::: "memory")
#define WAITLGKM0() asm volatile("s_waitcnt lgkmcnt(0)" ::: "memory")
#define SB0() __builtin_amdgcn_sched_barrier(0)
#define BARRIER() do { SB0(); WAITLGKM0(); __builtin_amdgcn_s_barrier(); SB0(); } while (0)

__global__ __launch_bounds__(512, 4)
void mvh_gemm(const float* __restrict__ hidden, const short* __restrict__ Wswz,
              const float* __restrict__ bias, float* __restrict__ logits) {
    __shared__ __align__(16) char lds[2 * A_TILE + 2 * B_TILE];   // 45056 B
    char* A0 = lds;
    char* A1 = lds + A_TILE;
    char* B0 = lds + 2 * A_TILE;
    char* B1 = lds + 2 * A_TILE + B_TILE;

    const int tid  = threadIdx.x;
    const int lane = tid & 63;
    const int wave = tid >> 6;          // 0..7
    const int kph   = wave >> 2;        // tile-parity owner
    const int wsub  = (wave >> 1) & 1;  // 32-row slice
    const int nhalf = wave & 1;         // 144-col half
    const int l15 = lane & 15, lhi = lane >> 4;
    const int rowbase = blockIdx.x * 64;

    // A staging: thread t loads 4 floats: row r=t>>3, k4=(t&7)*4 (128B/row x8thr)
    const int ar = tid >> 3;
    const int ak4 = (tid & 7) * 4;
    const float* gAbase = hidden + (size_t)(rowbase + ar) * DIM + ak4;
    // LDS dest: frag=ar>>4, fraglane=(ar&15)+16*(ak4>>3), byte half (ak4&4)*2
    const int awbyte = (ar >> 4) * 1024 + ((ar & 15) + 16 * (ak4 >> 3)) * 16 + (ak4 & 4) * 2;

    f32x4 acc0[9], acc1[9];
    #pragma unroll
    for (int n = 0; n < 9; n++) { acc0[n] = (f32x4)0.0f; acc1[n] = (f32x4)0.0f; }

    f32x4 ga0, ga1;   // A in flight: slot = tile parity

#define LOADA(slot, kt) do { \
    slot = *(const f32x4*)(gAbase + (kt) * 32); \
    SB0(); \
} while (0)

#define STAGE_B(dst, kt) do { \
    _Pragma("unroll") \
    for (int i_ = 0; i_ < 3; i_++) { \
        if (i_ < 2 || tid < 128) { \
            int g_ = (i_ < 2) ? (i_ * 512 + tid) : (1024 + tid); \
            const short* gp_ = Wswz + (size_t)((g_ >> 6) * 64 + (kt)) * 512 + (g_ & 63) * 8; \
            char* lp_ = (dst) + g_ * 16; \
            __builtin_amdgcn_global_load_lds((const __attribute__((address_space(1))) void*)gp_, \
                (__attribute__((address_space(3))) void*)lp_, 16, 0, 0); \
        } \
    } \
    SB0(); \
} while (0)

#define WRITEA(dst, slot) do { \
    short s0_ = f2bf(slot[0]), s1_ = f2bf(slot[1]), s2_ = f2bf(slot[2]), s3_ = f2bf(slot[3]); \
    typedef __attribute__((ext_vector_type(4))) short short4_; \
    short4_ w_; w_[0] = s0_; w_[1] = s1_; w_[2] = s2_; w_[3] = s3_; \
    *(short4_*)((dst) + awbyte) = w_; \
} while (0)

#define COMPUTE(Ab, Bb) do { \
    short8 af0_ = *(const short8*)((Ab) + (wsub * 2 + 0) * 1024 + lane * 16); \
    short8 af1_ = *(const short8*)((Ab) + (wsub * 2 + 1) * 1024 + lane * 16); \
    _Pragma("unroll") \
    for (int n_ = 0; n_ < 9; n_++) { \
        short8 bf_ = *(const short8*)((Bb) + (nhalf * 9 + n_) * 1024 + lane * 16); \
        acc0[n_] = __builtin_amdgcn_mfma_f32_16x16x32_bf16(af0_, bf_, acc0[n_], 0, 0, 0); \
        acc1[n_] = __builtin_amdgcn_mfma_f32_16x16x32_bf16(af1_, bf_, acc1[n_], 0, 0, 0); \
    } \
} while (0)

    // ---- prologue ----
    LOADA(ga0, 0);
    WAITVM(0); SB0();
    WRITEA(A0, ga0);
    STAGE_B(B0, 0);          // 2-3 DMA issues
    LOADA(ga1, 1);           // A(1) in flight
    WAITVM(1);               // B(0) retired; A(1) still flying
    BARRIER();

    // ---- main loop: one raw barrier per tile ----
    #pragma unroll 1
    for (int t = 0; t < 62; t += 2) {
        // even tile t: compute buf0, stage B(t+1)->B1, issue A(t+2)->ga0,
        // write A(t+1) (ga1) -> A1.
        STAGE_B(B1, t + 1);
        LOADA(ga0, t + 2);
        if (kph == 0) COMPUTE(A0, B0);
        WAITVM(1); SB0();                // retire A(t+1)+B(t+1); A(t+2) flying
        WRITEA(A1, ga1);
        BARRIER();
        // odd tile t+1: compute buf1, stage B(t+2)->B0, issue A(t+3)->ga1,
        // write A(t+2) (ga0) -> A0.
        STAGE_B(B0, t + 2);
        if (t + 3 < 64) LOADA(ga1, t + 3);
        if (kph == 1) COMPUTE(A1, B1);
        if (t + 3 < 64) { WAITVM(1); } else { WAITVM(0); }
        SB0();
        WRITEA(A0, ga0);
        BARRIER();
    }
    // tile 62: stage B(63)->B1, write A(63) (ga1) -> A1. Nothing left to issue.
    STAGE_B(B1, 63);
    if (kph == 0) COMPUTE(A0, B0);
    WAITVM(0); SB0();
    WRITEA(A1, ga1);
    BARRIER();
    // tile 63
    if (kph == 1) COMPUTE(A1, B1);

#undef LOADA
#undef STAGE_B
#undef WRITEA
#undef COMPUTE

    // ---- epilogue: cross-kph reduction (2 phases), bias, store ----
#define RED_PHASE(ACC, MOFS) do { \
    __syncthreads(); \
    if (kph == 1) { \
        char* dst_ = lds + (wave & 3) * 9216; \
        _Pragma("unroll") \
        for (int n_ = 0; n_ < 9; n_++) \
            *(f32x4*)(dst_ + (n_ * 64 + lane) * 16) = ACC[n_]; \
    } \
    __syncthreads(); \
    if (kph == 0) { \
        const char* src_ = lds + wave * 9216; \
        _Pragma("unroll") \
        for (int n_ = 0; n_ < 9; n_++) { \
            f32x4 p_ = *(const f32x4*)(src_ + (n_ * 64 + lane) * 16); \
            int c_ = nhalf * 144 + n_ * 16 + l15; \
            if (c_ < NCOLS) { \
                float bv_ = bias[c_]; \
                int row0_ = rowbase + wsub * 32 + (MOFS) * 16 + lhi * 4; \
                _Pragma("unroll") \
                for (int r_ = 0; r_ < 4; r_++) \
                    logits[(size_t)(row0_ + r_) * NCOLS + c_] = ACC[n_][r_] + p_[r_] + bv_; \
            } \
        } \
    } \
} while (0)

    RED_PHASE(acc0, 0);
    RED_PHASE(acc1, 1);
#undef RED_PHASE
}

// ---------------------------------------------------------------------------
// Loss: one thread per (row, head). nll = logsumexp(10) - x[label].
// ---------------------------------------------------------------------------
__global__ __launch_bounds__(256)
void mvh_loss(const float* __restrict__ logits, const int* __restrict__ labels,
              float* __restrict__ loss_out) {
    int gid = blockIdx.x * 256 + threadIdx.x;    // 917504 = 3584*256 exactly
    const float* p = logits + (size_t)gid * 10;
    float x[10];
    #pragma unroll
    for (int j = 0; j < 10; j++) x[j] = p[j];
    float m = x[0];
    #pragma unroll
    for (int j = 1; j < 10; j++) m = fmaxf(m, x[j]);
    float s = 0.0f;
    #pragma unroll
    for (int j = 0; j < 10; j++) s += __expf(x[j] - m);
    int lab = labels[gid];
    float xl = x[0];
    #pragma unroll
    for (int j = 1; j < 10; j++) xl = (lab == j) ? x[j] : xl;
    float nll = m + __logf(s) - xl;

    #pragma unroll
    for (int off = 32; off > 0; off >>= 1)
        nll += __shfl_down(nll, off, 64);

    __shared__ float part[4];
    int lane = threadIdx.x & 63, wv = threadIdx.x >> 6;
    if (lane == 0) part[wv] = nll;
    __syncthreads();
    if (threadIdx.x == 0)
        atomicAdd(loss_out, (part[0] + part[1] + part[2] + part[3]) * LOSS_SCALE);
}

extern "C" void kernel_launch(void* const* d_in, const int* in_sizes, int n_in,
                              void* d_out, int out_size, void* d_ws, size_t ws_size,
                              hipStream_t stream) {
    const float* hidden = (const float*)d_in[0];
    const int* labels   = (const int*)d_in[1];
    const float* W      = (const float*)d_in[2];
    const float* bias   = (const float*)d_in[3];
    float* out = (float*)d_out;
    short* Wswz = (short*)d_ws;   // 589824 bf16 = 1.18 MB

    hipMemsetAsync(d_out, 0, sizeof(float), stream);           // zero loss accumulator
    mvh_swz<<<288, 256, 0, stream>>>(W, Wswz);
    mvh_gemm<<<512, 512, 0, stream>>>(hidden, Wswz, bias, out + 1);
    mvh_loss<<<3584, 256, 0, stream>>>(out + 1, labels, out);
}

// Round 8
// 142.068 us; speedup vs baseline: 1.0901x; 1.0308x over previous
//
#include <hip/hip_runtime.h>
#include <hip/hip_bf16.h>

#define BATCH   32768
#define DIM     2048
#define NHEADS  28
#define NCOLS   280
#define LOSS_SCALE (1.0f / (float)(BATCH * NHEADS))

typedef __attribute__((ext_vector_type(8))) short short8;
typedef __attribute__((ext_vector_type(4))) short s4vec;
typedef __attribute__((ext_vector_type(4))) float f32x4;

__device__ __forceinline__ short f2bf(float f) {
    union { __hip_bfloat16 h; short s; } u; u.h = __float2bfloat16(f); return u.s;
}

// ---------------------------------------------------------------------------
// W pre-swizzle: W [280][2048] f32 -> Wswz bf16 in MFMA B-fragment order.
//   short index = (nt*64 + kt)*512 + lane*8 + j
//   n = nt*16 + (lane&15), d = kt*32 + (lane>>4)*8 + j   (kt = BK=32 tile idx)
// ---------------------------------------------------------------------------
__global__ void mvh_swz(const float* __restrict__ W, short* __restrict__ Wswz) {
    int t = blockIdx.x * 256 + threadIdx.x;      // 73728 threads
    int lane = t & 63;
    int ks = (t >> 6) & 63;
    int nt = t >> 12;                            // 0..17
    int n = nt * 16 + (lane & 15);
    int d = ks * 32 + (lane >> 4) * 8;
    short8 v;
    #pragma unroll
    for (int j = 0; j < 8; j++) v[j] = 0;
    if (n < NCOLS) {
        const float* src = W + (size_t)n * DIM + d;
        #pragma unroll
        for (int j = 0; j < 8; j++) v[j] = f2bf(src[j]);
    }
    *(short8*)(Wswz + (size_t)t * 8) = v;
}

// ---------------------------------------------------------------------------
// GEMM: logits[b][n] = sum_d hidden[b][d]*W[n][d] + bias[n]
// grid 512 x 512 threads (8 waves), 2 blocks/CU = 16 waves/CU.
// BM=64, BK=32, 64 K-tiles processed in 16 GROUPS of 4 tiles.
// KEY CHANGE vs r6: A is loaded one GROUP (4 tiles) at a time — each thread
// issues 4 back-to-back dwordx4 so each DRAM row gives 512B contiguous in one
// open-row window (fixes the 128B/8KB-stride row-activation thrash that
// capped every prior round at ~2.1 TB/s on the A stream).
// A regs -> bf16 frag-major LDS one group ahead (2-group dbuf).
// B: global_load_lds DMA from L2-resident frag-ordered Wswz (2-tile dbuf).
// Waves: kph=w>>2 computes tiles of matching parity (M_rep=2, acc 2x9 f32x4);
// plain __syncthreads per tile (equal to counted-vmcnt per r6 evidence).
// Epilogue: 2-phase cross-kph LDS reduction + bias + store.
// ---------------------------------------------------------------------------
#define A_GRP  16384                 // 4 tiles * 4KB bf16 frag-major
#define B_TILE 18432                 // 18 frags * 1KB

#define SB0() __builtin_amdgcn_sched_barrier(0)

__global__ __launch_bounds__(512, 4)
void mvh_gemm(const float* __restrict__ hidden, const short* __restrict__ Wswz,
              const float* __restrict__ bias, float* __restrict__ logits) {
    __shared__ __align__(16) char lds[2 * A_GRP + 2 * B_TILE];   // 69632 B
    char* B0 = lds + 2 * A_GRP;
    char* B1 = lds + 2 * A_GRP + B_TILE;

    const int tid  = threadIdx.x;
    const int lane = tid & 63;
    const int wave = tid >> 6;          // 0..7
    const int kph   = wave >> 2;        // tile-parity owner
    const int wsub  = (wave >> 1) & 1;  // 32-row slice
    const int nhalf = wave & 1;         // 144-col half
    const int l15 = lane & 15, lhi = lane >> 4;
    const int rowbase = blockIdx.x * 64;

    // A staging: thread t covers row ar = t>>3, 16B chunk (t&7) of each slot.
    const int ar  = tid >> 3;
    const int ak4 = (tid & 7) * 4;
    const float* gAbase = hidden + (size_t)(rowbase + ar) * DIM + ak4;
    // frag-major LDS dest within a 4KB tile slot
    const int awbyte = (ar >> 4) * 1024 + ((ar & 15) + 16 * (ak4 >> 3)) * 16 + (ak4 & 4) * 2;

    f32x4 acc0[9], acc1[9];
    #pragma unroll
    for (int n = 0; n < 9; n++) { acc0[n] = (f32x4)0.0f; acc1[n] = (f32x4)0.0f; }

    f32x4 ga0, ga1, ga2, ga3;   // one A-group in flight (named slots, rule #20)

#define LOADA4(grp) do { \
    const float* p_ = gAbase + (size_t)(grp) * 128; \
    ga0 = *(const f32x4*)(p_);      ga1 = *(const f32x4*)(p_ + 32); \
    ga2 = *(const f32x4*)(p_ + 64); ga3 = *(const f32x4*)(p_ + 96); \
    SB0(); \
} while (0)

#define WRA1(dst, slot, src) do { \
    s4vec w_; \
    w_[0] = f2bf(src[0]); w_[1] = f2bf(src[1]); w_[2] = f2bf(src[2]); w_[3] = f2bf(src[3]); \
    *(s4vec*)((dst) + (slot) * 4096 + awbyte) = w_; \
} while (0)

#define WRITEA4(dst) do { \
    WRA1(dst, 0, ga0); WRA1(dst, 1, ga1); WRA1(dst, 2, ga2); WRA1(dst, 3, ga3); \
} while (0)

#define STAGE_B(dst, kt) do { \
    _Pragma("unroll") \
    for (int i_ = 0; i_ < 3; i_++) { \
        if (i_ < 2 || tid < 128) { \
            int g_ = (i_ < 2) ? (i_ * 512 + tid) : (1024 + tid); \
            const short* gp_ = Wswz + (size_t)((g_ >> 6) * 64 + (kt)) * 512 + (g_ & 63) * 8; \
            char* lp_ = (dst) + g_ * 16; \
            __builtin_amdgcn_global_load_lds((const __attribute__((address_space(1))) void*)gp_, \
                (__attribute__((address_space(3))) void*)lp_, 16, 0, 0); \
        } \
    } \
    SB0(); \
} while (0)

#define COMPUTE(Abase, Bb) do { \
    short8 af0_ = *(const short8*)((Abase) + (wsub * 2 + 0) * 1024 + lane * 16); \
    short8 af1_ = *(const short8*)((Abase) + (wsub * 2 + 1) * 1024 + lane * 16); \
    _Pragma("unroll") \
    for (int n_ = 0; n_ < 9; n_++) { \
        short8 bf_ = *(const short8*)((Bb) + (nhalf * 9 + n_) * 1024 + lane * 16); \
        acc0[n_] = __builtin_amdgcn_mfma_f32_16x16x32_bf16(af0_, bf_, acc0[n_], 0, 0, 0); \
        acc1[n_] = __builtin_amdgcn_mfma_f32_16x16x32_bf16(af1_, bf_, acc1[n_], 0, 0, 0); \
    } \
} while (0)

    // ---- prologue: group 0 -> A-buf 0; B(0) -> B0; group 1 -> regs ----
    LOADA4(0);
    WRITEA4(lds);            // compiler inserts the vmcnt for the reg dep
    STAGE_B(B0, 0);
    LOADA4(1);
    __syncthreads();

    // ---- main loop: 16 groups x 4 tiles, one __syncthreads per tile ----
    #pragma unroll 1
    for (int g = 0; g < 16; g++) {
        const int t0 = g * 4;
        char* Ac = lds + (g & 1) * A_GRP;
        char* An = lds + ((g & 1) ^ 1) * A_GRP;
        // i=0 (tile t0, even): write next A-group to LDS, stage B(t0+1)
        if (g < 15) WRITEA4(An);
        STAGE_B(B1, t0 + 1);
        if (kph == 0) COMPUTE(Ac, B0);
        __syncthreads();
        // i=1 (odd): issue next A-group loads (512B/row, DRAM-adjacent)
        if (g < 14) LOADA4(g + 2);
        STAGE_B(B0, t0 + 2);
        if (kph == 1) COMPUTE(Ac + 4096, B1);
        __syncthreads();
        // i=2 (even)
        STAGE_B(B1, t0 + 3);
        if (kph == 0) COMPUTE(Ac + 8192, B0);
        __syncthreads();
        // i=3 (odd)
        if (g < 15) STAGE_B(B0, t0 + 4);
        if (kph == 1) COMPUTE(Ac + 12288, B1);
        __syncthreads();
    }

#undef LOADA4
#undef WRA1
#undef WRITEA4
#undef STAGE_B
#undef COMPUTE

    // ---- epilogue: cross-kph reduction (2 phases), bias, store ----
#define RED_PHASE(ACC, MOFS) do { \
    __syncthreads(); \
    if (kph == 1) { \
        char* dst_ = lds + (wave & 3) * 9216; \
        _Pragma("unroll") \
        for (int n_ = 0; n_ < 9; n_++) \
            *(f32x4*)(dst_ + (n_ * 64 + lane) * 16) = ACC[n_]; \
    } \
    __syncthreads(); \
    if (kph == 0) { \
        const char* src_ = lds + wave * 9216; \
        _Pragma("unroll") \
        for (int n_ = 0; n_ < 9; n_++) { \
            f32x4 p_ = *(const f32x4*)(src_ + (n_ * 64 + lane) * 16); \
            int c_ = nhalf * 144 + n_ * 16 + l15; \
            if (c_ < NCOLS) { \
                float bv_ = bias[c_]; \
                int row0_ = rowbase + wsub * 32 + (MOFS) * 16 + lhi * 4; \
                _Pragma("unroll") \
                for (int r_ = 0; r_ < 4; r_++) \
                    logits[(size_t)(row0_ + r_) * NCOLS + c_] = ACC[n_][r_] + p_[r_] + bv_; \
            } \
        } \
    } \
} while (0)

    RED_PHASE(acc0, 0);
    RED_PHASE(acc1, 1);
#undef RED_PHASE
}

// ---------------------------------------------------------------------------
// Loss: one thread per (row, head). nll = logsumexp(10) - x[label].
// ---------------------------------------------------------------------------
__global__ __launch_bounds__(256)
void mvh_loss(const float* __restrict__ logits, const int* __restrict__ labels,
              float* __restrict__ loss_out) {
    int gid = blockIdx.x * 256 + threadIdx.x;    // 917504 = 3584*256 exactly
    const float* p = logits + (size_t)gid * 10;
    float x[10];
    #pragma unroll
    for (int j = 0; j < 10; j++) x[j] = p[j];
    float m = x[0];
    #pragma unroll
    for (int j = 1; j < 10; j++) m = fmaxf(m, x[j]);
    float s = 0.0f;
    #pragma unroll
    for (int j = 0; j < 10; j++) s += __expf(x[j] - m);
    int lab = labels[gid];
    float xl = x[0];
    #pragma unroll
    for (int j = 1; j < 10; j++) xl = (lab == j) ? x[j] : xl;
    float nll = m + __logf(s) - xl;

    #pragma unroll
    for (int off = 32; off > 0; off >>= 1)
        nll += __shfl_down(nll, off, 64);

    __shared__ float part[4];
    int lane = threadIdx.x & 63, wv = threadIdx.x >> 6;
    if (lane == 0) part[wv] = nll;
    __syncthreads();
    if (threadIdx.x == 0)
        atomicAdd(loss_out, (part[0] + part[1] + part[2] + part[3]) * LOSS_SCALE);
}

extern "C" void kernel_launch(void* const* d_in, const int* in_sizes, int n_in,
                              void* d_out, int out_size, void* d_ws, size_t ws_size,
                              hipStream_t stream) {
    const float* hidden = (const float*)d_in[0];
    const int* labels   = (const int*)d_in[1];
    const float* W      = (const float*)d_in[2];
    const float* bias   = (const float*)d_in[3];
    float* out = (float*)d_out;
    short* Wswz = (short*)d_ws;   // 589824 bf16 = 1.18 MB

    (void)hipMemsetAsync(d_out, 0, sizeof(float), stream);     // zero loss accumulator
    mvh_swz<<<288, 256, 0, stream>>>(W, Wswz);
    mvh_gemm<<<512, 512, 0, stream>>>(hidden, Wswz, bias, out + 1);
    mvh_loss<<<3584, 256, 0, stream>>>(out + 1, labels, out);
}